// Round 8
// baseline (930.767 us; speedup 1.0000x reference)
//
#include <hip/hip_runtime.h>
#include <cstdint>
#include <cstddef>

// x[4096,4096] fp32, qweight[16384,4096] int32(int8 vals), scales[16384,128] fp32,
// bias[16384] fp32. out[4096,16384] = x @ W^T + b, fp32.
#define M_DIM 4096
#define N_DIM 16384
#define K_DIM 4096
#define QBLK 32

typedef __bf16 bf16x8 __attribute__((ext_vector_type(8)));
typedef float  f32x4  __attribute__((ext_vector_type(4)));
typedef unsigned short u16x8 __attribute__((ext_vector_type(8)));

__device__ __forceinline__ unsigned short f2bf(float f) {
    unsigned int x = __builtin_bit_cast(unsigned int, f);
    x += 0x7fffu + ((x >> 16) & 1u);
    return (unsigned short)(x >> 16);
}

__device__ __forceinline__ void gload16(const void* g, void* l) {
    __builtin_amdgcn_global_load_lds((__attribute__((address_space(1))) unsigned int*)(g),
                                     (__attribute__((address_space(3))) unsigned int*)(l),
                                     16, 0, 0);
}

// ---------------- pre-pass: x fp32 -> bf16 ----------------
__global__ __launch_bounds__(256) void cvt_x_kernel(const float* __restrict__ x,
                                                    unsigned short* __restrict__ o) {
    const size_t total = (size_t)M_DIM * K_DIM / 8;
    for (size_t i = (size_t)blockIdx.x * 256 + threadIdx.x; i < total;
         i += (size_t)gridDim.x * 256) {
        const float4* src = (const float4*)(x + i * 8);
        float4 a0 = src[0], a1 = src[1];
        u16x8 v;
        v[0] = f2bf(a0.x); v[1] = f2bf(a0.y); v[2] = f2bf(a0.z); v[3] = f2bf(a0.w);
        v[4] = f2bf(a1.x); v[5] = f2bf(a1.y); v[6] = f2bf(a1.z); v[7] = f2bf(a1.w);
        *(u16x8*)(o + i * 8) = v;
    }
}

// ---------------- pre-pass: W dequant -> bf16 ----------------
__global__ __launch_bounds__(256) void dequant_w_kernel(const int* __restrict__ q,
                                                        const float* __restrict__ s,
                                                        unsigned short* __restrict__ o) {
    const size_t total = (size_t)N_DIM * K_DIM / 8;
    for (size_t i = (size_t)blockIdx.x * 256 + threadIdx.x; i < total;
         i += (size_t)gridDim.x * 256) {
        const int4* src = (const int4*)(q + i * 8);
        int4 q0 = src[0], q1 = src[1];
        float sc = s[i >> 2];
        u16x8 v;
        v[0] = f2bf((float)q0.x * sc); v[1] = f2bf((float)q0.y * sc);
        v[2] = f2bf((float)q0.z * sc); v[3] = f2bf((float)q0.w * sc);
        v[4] = f2bf((float)q1.x * sc); v[5] = f2bf((float)q1.y * sc);
        v[6] = f2bf((float)q1.z * sc); v[7] = f2bf((float)q1.w * sc);
        *(u16x8*)(o + i * 8) = v;
    }
}

// ---------------- main GEMM: 256x256 tile, BK=64, 8 waves, 2-barrier counted-lgkm ----
// Wave (wm,wn) owns rows {mh*128 + wm*64 + mf*16} x cols {nh*128 + wn*32 + nf*16}.
// LDS: 2 dbuf x (A: 2 halves x 16KB, B: 2 halves x 16KB) = 128 KiB.
// Per tile: issue ALL 24 ds_read_b128 upfront (order pinned A0,B0,A1,B1 by mem fences),
// MFMA quadrants gated by counted lgkmcnt(12/4/0) + sched_barrier (rule #18).
// Only 2 s_barrier per tile: before re-staging own buf (t+2 halves) and at tile end
// after vmcnt(4) (waits t+1's A1,B1; t+2's A0,B0 stay in flight — T4, never vmcnt(0)).
__global__ __launch_bounds__(512, 2) void gemm256(
    const unsigned short* __restrict__ Abf, const unsigned short* __restrict__ Bbf,
    const float* __restrict__ bias, float* __restrict__ out) {

    __shared__ char smem[131072];

    const int t  = threadIdx.x;
    const int l  = t & 63;
    const int w  = t >> 6;       // wave 0..7
    const int wm = w >> 2;       // 0..1
    const int wn = w & 3;        // 0..3

    // XCD-aware bijective swizzle (nwg = 1024, %8 == 0)
    const int bid = blockIdx.y * 64 + blockIdx.x;
    const int wg  = (bid & 7) * 128 + (bid >> 3);
    const int bx  = wg & 63;
    const int by  = wg >> 6;
    const int tileM = by * 256;
    const int tileN = bx * 256;

    // staging: thread covers row sr (within 64-row j-half), swizzled chunk cs
    const int sr = w * 8 + (l >> 3);
    const int cs = (l & 7) ^ (l >> 3);
    const char* aP = (const char*)Abf + (size_t)(tileM + sr) * (K_DIM * 2) + cs * 16;
    const char* bP = (const char*)Bbf + (size_t)(tileN + sr) * (K_DIM * 2) + cs * 16;
    const int wq = w * 1024;

    // ds_read per-lane offsets (within a 16KB half): addr = row*128 + (chunk^(row&7))*16
    const int lrow = l & 15, l47 = l >> 4;
    const int sw = lrow & 7;
    const unsigned c0 = (unsigned)((l47 ^ sw) * 16);
    const unsigned c1 = (unsigned)(((4 + l47) ^ sw) * 16);
    const unsigned offA0 = (unsigned)((wm * 64 + lrow) * 128) + c0;
    const unsigned offA1 = (unsigned)((wm * 64 + lrow) * 128) + c1;
    const unsigned offB0 = (unsigned)((wn * 32 + lrow) * 128) + c0;
    const unsigned offB1 = (unsigned)((wn * 32 + lrow) * 128) + c1;

    bf16x8 avr0[4][2], avr1[4][2];   // A frags per mh-half (mf, kk)
    bf16x8 bvr0[2][2], bvr1[2][2];   // B frags per nh-half (nf, kk)
    f32x4  acc[2][4][2][2] = {};     // (mh, mf, nh, nf)

#define ST_A(H, KT, DB) do { \
    const char* g_ = aP + (size_t)(H) * 1048576u + (unsigned)(KT) * 128u; \
    char* d_ = smem + (DB) * 65536 + (H) * 16384 + wq; \
    gload16(g_, d_); gload16(g_ + 524288, d_ + 8192); } while (0)

#define ST_B(H, KT, DB) do { \
    const char* g_ = bP + (size_t)(H) * 1048576u + (unsigned)(KT) * 128u; \
    char* d_ = smem + (DB) * 65536 + 32768 + (H) * 16384 + wq; \
    gload16(g_, d_); gload16(g_ + 524288, d_ + 8192); } while (0)

#define RD_A(DB, MH, DST) do { \
    const char* b_ = smem + (DB) * 65536 + (MH) * 16384; \
    _Pragma("unroll") for (int mf_ = 0; mf_ < 4; ++mf_) { \
        DST[mf_][0] = *(const bf16x8*)(b_ + offA0 + mf_ * 2048); \
        DST[mf_][1] = *(const bf16x8*)(b_ + offA1 + mf_ * 2048); } } while (0)

#define RD_B(DB, NH, DST) do { \
    const char* b_ = smem + (DB) * 65536 + 32768 + (NH) * 16384; \
    _Pragma("unroll") for (int nf_ = 0; nf_ < 2; ++nf_) { \
        DST[nf_][0] = *(const bf16x8*)(b_ + offB0 + nf_ * 2048); \
        DST[nf_][1] = *(const bf16x8*)(b_ + offB1 + nf_ * 2048); } } while (0)

#define MMQ(MH, NH, AV, BV) do { __builtin_amdgcn_s_setprio(1); \
    _Pragma("unroll") for (int mf_ = 0; mf_ < 4; ++mf_) \
    _Pragma("unroll") for (int nf_ = 0; nf_ < 2; ++nf_) \
    _Pragma("unroll") for (int kk_ = 0; kk_ < 2; ++kk_) \
        acc[MH][mf_][NH][nf_] = __builtin_amdgcn_mfma_f32_16x16x32_bf16( \
            AV[mf_][kk_], BV[nf_][kk_], acc[MH][mf_][NH][nf_], 0, 0, 0); \
    __builtin_amdgcn_s_setprio(0); } while (0)

#define BAR   __builtin_amdgcn_s_barrier()
#define FENCE asm volatile("" ::: "memory")   // pin ds_read issue order (no instr)
#define LGKM(N) do { asm volatile("s_waitcnt lgkmcnt(" #N ")" ::: "memory"); \
                     __builtin_amdgcn_sched_barrier(0); } while (0)
#define VMC(N) asm volatile("s_waitcnt vmcnt(" #N ")" ::: "memory")

    // prologue: tile0 fully staged (8 loads) + A0,B0 of tile1 in flight (4 loads)
    ST_A(0, 0, 0); ST_B(0, 0, 0); ST_A(1, 0, 0); ST_B(1, 0, 0);
    ST_A(0, 1, 1); ST_B(0, 1, 1);
    VMC(4); BAR;

    // TILE body: tile KT in buf DB. Issue order of the 24 lgkm ops is load-bearing:
    // [A0(8), B0(4)] -> lgkm(12); [A1(8)] -> lgkm(4); [B1(4)] -> lgkm(0).
#define TILE(KT, DB) do { \
    RD_A(DB, 0, avr0); RD_B(DB, 0, bvr0); FENCE; \
    RD_A(DB, 1, avr1); FENCE; \
    RD_B(DB, 1, bvr1); FENCE; \
    ST_A(1, ((KT) + 1) & 63, (DB) ^ 1); ST_B(1, ((KT) + 1) & 63, (DB) ^ 1); \
    LGKM(12); MMQ(0, 0, avr0, bvr0); \
    LGKM(4);  MMQ(1, 0, avr1, bvr0); \
    LGKM(0);  MMQ(0, 1, avr0, bvr1); \
    BAR; \
    ST_A(0, ((KT) + 2) & 63, DB); ST_B(0, ((KT) + 2) & 63, DB); \
    MMQ(1, 1, avr1, bvr1); \
    VMC(4); BAR; } while (0)

    for (int i = 0; i < 32; ++i) {
        const int k0 = 2 * i;
        TILE(k0, 0);
        TILE(k0 + 1, 1);
    }

    VMC(0);   // drain tail prefetches before epilogue

    // epilogue: C/D layout col = lane&15, row = (lane>>4)*4 + reg
    #pragma unroll
    for (int mh = 0; mh < 2; ++mh)
    #pragma unroll
    for (int nh = 0; nh < 2; ++nh)
    #pragma unroll
    for (int nf = 0; nf < 2; ++nf) {
        const int col = tileN + nh * 128 + wn * 32 + nf * 16 + lrow;
        const float bv = bias[col];
        #pragma unroll
        for (int mf = 0; mf < 4; ++mf) {
            const int row0 = tileM + mh * 128 + wm * 64 + mf * 16 + l47 * 4;
            f32x4 v = acc[mh][mf][nh][nf];
            #pragma unroll
            for (int j = 0; j < 4; ++j)
                out[(size_t)(row0 + j) * N_DIM + col] = v[j] + bv;
        }
    }
#undef ST_A
#undef ST_B
#undef RD_A
#undef RD_B
#undef MMQ
#undef BAR
#undef FENCE
#undef LGKM
#undef VMC
#undef TILE
}

// ---------------- fallback fused 128x128 kernel (only if ws too small) ----------------
__global__ __launch_bounds__(256, 2) void gemm_fused(
    const float* __restrict__ Xf, const int* __restrict__ Qw, const float* __restrict__ Sc,
    const float* __restrict__ bias, float* __restrict__ out) {

    __shared__ char smem[2 * 32768];
    const int t = threadIdx.x;
    const int l = t & 63;
    const int w = t >> 6;
    const int wm = w >> 1, wn = w & 1;
    const int rowA0 = blockIdx.y * 128;
    const int colB0 = blockIdx.x * 128;

    const int lr = l >> 3;
    const int sXor = (l & 7) ^ lr;

    const float* aSrcF[4]; const int* bSrcQ[4]; const float* bSrcS[4];
    #pragma unroll
    for (int j = 0; j < 4; ++j) {
        int c = w * 4 + j;
        aSrcF[j] = Xf + (size_t)(rowA0 + c * 8 + lr) * K_DIM + sXor * 8;
        bSrcQ[j] = Qw + (size_t)(colB0 + c * 8 + lr) * K_DIM + sXor * 8;
        bSrcS[j] = Sc + (size_t)(colB0 + c * 8 + lr) * (K_DIM / QBLK) + (sXor >> 2);
    }

    const int lrow = l & 15, l47 = l >> 4, lx = l & 7;
    const unsigned raB0 = (unsigned)((wm * 64 + lrow) * 128 + ((l47 ^ lx) * 16));
    const unsigned raB1 = (unsigned)((wm * 64 + lrow) * 128 + (((4 | l47) ^ lx) * 16));
    const unsigned rbB0 = (unsigned)(16384 + (wn * 64 + lrow) * 128 + ((l47 ^ lx) * 16));
    const unsigned rbB1 = (unsigned)(16384 + (wn * 64 + lrow) * 128 + (((4 | l47) ^ lx) * 16));

    float fA[4][8]; int qB[4][8]; float sB[4];
    auto load_s = [&]() {
        #pragma unroll
        for (int j = 0; j < 4; ++j) {
            float4 a0 = ((const float4*)aSrcF[j])[0];
            float4 a1 = ((const float4*)aSrcF[j])[1];
            fA[j][0] = a0.x; fA[j][1] = a0.y; fA[j][2] = a0.z; fA[j][3] = a0.w;
            fA[j][4] = a1.x; fA[j][5] = a1.y; fA[j][6] = a1.z; fA[j][7] = a1.w;
            aSrcF[j] += 64;
            int4 b0 = ((const int4*)bSrcQ[j])[0];
            int4 b1 = ((const int4*)bSrcQ[j])[1];
            qB[j][0] = b0.x; qB[j][1] = b0.y; qB[j][2] = b0.z; qB[j][3] = b0.w;
            qB[j][4] = b1.x; qB[j][5] = b1.y; qB[j][6] = b1.z; qB[j][7] = b1.w;
            bSrcQ[j] += 64;
            sB[j] = *bSrcS[j]; bSrcS[j] += 2;
        }
    };
    auto write_s = [&](int bsel) {
        #pragma unroll
        for (int j = 0; j < 4; ++j) {
            u16x8 va, vb;
            #pragma unroll
            for (int e = 0; e < 8; ++e) va[e] = f2bf(fA[j][e]);
            #pragma unroll
            for (int e = 0; e < 8; ++e) vb[e] = f2bf((float)qB[j][e] * sB[j]);
            *(u16x8*)(&smem[bsel * 32768 + (w * 4 + j) * 1024 + l * 16]) = va;
            *(u16x8*)(&smem[bsel * 32768 + 16384 + (w * 4 + j) * 1024 + l * 16]) = vb;
        }
    };

    f32x4 acc[4][4] = {};
    load_s(); write_s(0);
    __syncthreads();
    int bsel = 0;
    for (int kt = 0; kt < 64; ++kt) {
        const bool pre = (kt + 1 < 64);
        if (pre) load_s();
        const unsigned boff = (unsigned)(bsel * 32768);
        #pragma unroll
        for (int kk = 0; kk < 2; ++kk) {
            bf16x8 av[4], bv[4];
            const unsigned ra = (kk ? raB1 : raB0) + boff;
            const unsigned rb = (kk ? rbB1 : rbB0) + boff;
            #pragma unroll
            for (int mf = 0; mf < 4; ++mf) av[mf] = *(const bf16x8*)(&smem[ra + mf * 2048]);
            #pragma unroll
            for (int nf = 0; nf < 4; ++nf) bv[nf] = *(const bf16x8*)(&smem[rb + nf * 2048]);
            #pragma unroll
            for (int mf = 0; mf < 4; ++mf)
                #pragma unroll
                for (int nf = 0; nf < 4; ++nf)
                    acc[mf][nf] = __builtin_amdgcn_mfma_f32_16x16x32_bf16(
                        av[mf], bv[nf], acc[mf][nf], 0, 0, 0);
        }
        if (pre) write_s(bsel ^ 1);
        __syncthreads();
        bsel ^= 1;
    }
    const int orow0 = rowA0 + wm * 64 + l47 * 4;
    const int ocol0 = colB0 + wn * 64 + lrow;
    #pragma unroll
    for (int nf = 0; nf < 4; ++nf) {
        const float bv = bias[ocol0 + nf * 16];
        #pragma unroll
        for (int mf = 0; mf < 4; ++mf) {
            f32x4 v = acc[mf][nf];
            #pragma unroll
            for (int j = 0; j < 4; ++j)
                out[(size_t)(orow0 + mf * 16 + j) * N_DIM + (ocol0 + nf * 16)] = v[j] + bv;
        }
    }
}

extern "C" void kernel_launch(void* const* d_in, const int* in_sizes, int n_in,
                              void* d_out, int out_size, void* d_ws, size_t ws_size,
                              hipStream_t stream) {
    const float* x    = (const float*)d_in[0];
    const int*   qw   = (const int*)d_in[1];
    const float* sc   = (const float*)d_in[2];
    const float* bias = (const float*)d_in[3];
    float* out = (float*)d_out;

    const size_t need = ((size_t)M_DIM * K_DIM + (size_t)N_DIM * K_DIM) * 2;  // 160 MiB
    if (ws_size >= need) {
        unsigned short* xb = (unsigned short*)d_ws;
        unsigned short* wb = xb + (size_t)M_DIM * K_DIM;
        cvt_x_kernel<<<dim3(2048), dim3(256), 0, stream>>>(x, xb);
        dequant_w_kernel<<<dim3(4096), dim3(256), 0, stream>>>(qw, sc, wb);
        gemm256<<<dim3(64, 16), dim3(512), 0, stream>>>(xb, wb, bias, out);
    } else {
        gemm_fused<<<dim3(128, 32), dim3(256), 0, stream>>>(x, qw, sc, bias, out);
    }
}